// Round 11
// baseline (266.725 us; speedup 1.0000x reference)
//
#include <hip/hip_runtime.h>
#include <hip/hip_bf16.h>
#include <cmath>

#define T_SAMPLE 300
#define NCHUNK 75   // T / 4

typedef __attribute__((ext_vector_type(8))) short short8;
typedef __attribute__((ext_vector_type(4))) float f32x4;

struct RefK { float v[10]; };

// One step of the SLAYER spike recurrence. buf[0..9] = pending refractory.
__device__ __forceinline__ unsigned char spike_step(float u, float* buf, const RefK& rk) {
    const float um = u + buf[0];
    const bool fire = um >= 10.0f;
    const float ev = fire ? 1.0f : 0.0f;
#pragma unroll
    for (int r = 0; r < 9; ++r) buf[r] = fmaf(ev, rk.v[r], buf[r + 1]);
    buf[9] = ev * rk.v[9];
    return fire ? (unsigned char)1 : (unsigned char)0;
}

__device__ __forceinline__ int psum4(int g0, int g1, int g2, int g3, int sh) {
    return ((g0 >> sh) & 0xff) + ((g1 >> sh) & 0xff)
         + ((g2 >> sh) & 0xff) + ((g3 >> sh) & 0xff);
}

// byte->bf16 pack: 8 spike bytes (0/1) -> short8 of bf16 (1.0 = 0x3F80)
__device__ __forceinline__ short8 bytes_to_bf16x8(uint2 w8) {
    union { uint4 u; short8 s8; } cv;
    cv.u.x = (w8.x & 0xFFu) * 0x3F80u | ((((w8.x >> 8) & 0xFFu) * 0x3F80u) << 16);
    cv.u.y = ((w8.x >> 16) & 0xFFu) * 0x3F80u | ((((w8.x >> 24) & 0xFFu) * 0x3F80u) << 16);
    cv.u.z = (w8.y & 0xFFu) * 0x3F80u | ((((w8.y >> 8) & 0xFFu) * 0x3F80u) << 16);
    cv.u.w = ((w8.y >> 16) & 0xFFu) * 0x3F80u | ((((w8.y >> 24) & 0xFFu) * 0x3F80u) << 16);
    return cv.s8;
}

// 3-way exact bf16 split selector (24 mantissa bits = 3x8; residual 0)
__device__ __forceinline__ unsigned short bf16_split_sel(float w, int s) {
    __hip_bfloat16 hb = __float2bfloat16(w);
    const float hf = __bfloat162float(hb);
    __hip_bfloat16 mb = __float2bfloat16(w - hf);
    const float mf = __bfloat162float(mb);
    __hip_bfloat16 lb = __float2bfloat16(w - hf - mf);
    __hip_bfloat16 sel = (s == 0) ? hb : ((s == 1) ? mb : lb);
    return *(unsigned short*)&sel;
}

// ---------------------------------------------------------------------------
// transpose input [B,2,34,34,T] f32 ({0,1}) -> X[tchunk][n][4] u8, n = b,c,y,x
// ---------------------------------------------------------------------------
__global__ __launch_bounds__(256) void transpose_in_k(
    const float* __restrict__ In, unsigned int* __restrict__ X)
{
    __shared__ unsigned int lds[16 * NCHUNK];
    const int blk = blockIdx.x;          // 1156 blocks x 16 neurons
    const int tn = threadIdx.x >> 4;     // 0..15 neuron
    const int tq = threadIdx.x & 15;     // 0..15 t-group
    const size_t n = (size_t)blk * 16 + tn;
#pragma unroll
    for (int p = 0; p < 5; ++p) {
        const int ch = p * 16 + tq;
        if (ch < NCHUNK) {
            const float4 v = *(const float4*)(In + n * T_SAMPLE + ch * 4);
            unsigned int u = (v.x != 0.f ? 1u : 0u) | (v.y != 0.f ? 0x100u : 0u) |
                             (v.z != 0.f ? 0x10000u : 0u) | (v.w != 0.f ? 0x1000000u : 0u);
            lds[tn * NCHUNK + ch] = u;
        }
    }
    __syncthreads();
    for (int idx = threadIdx.x; idx < 16 * NCHUNK; idx += 256) {
        const int ch = idx >> 4, t2 = idx & 15;
        X[(size_t)ch * 18496 + blk * 16 + t2] = lds[t2 * NCHUNK + ch];
    }
}

// ---------------------------------------------------------------------------
// prep_w1: conv1 weights for MFMA, c-DUPLICATED packing. k = slot*4 + c2,
// slot = dy*6+dx (dx=5 and slot>=30 zero), c = c2&1, weight = w/2 (dup x2).
// Wr1[((s*4+ks)*64+lane)*8+j]: oc = lane&15, k = ks*32 + (lane>>4)*8 + j.
// ---------------------------------------------------------------------------
__global__ __launch_bounds__(256) void prep_w1_k(
    const float* __restrict__ w1, unsigned short* __restrict__ Wr1)
{
    const int g = blockIdx.x * 256 + threadIdx.x;   // 0..6143 (24 blocks exact)
    const int j = g & 7;
    const int lane = (g >> 3) & 63;
    const int ks = (g >> 9) & 3;
    const int s = g >> 11;               // 0..2
    const int q = lane >> 4;
    const int oc = lane & 15;
    const int kg = ks * 32 + q * 8 + j;
    const int slot = kg >> 2, c = kg & 1;
    const int dy = slot / 6, dx = slot % 6;
    const float w = (dy < 5 && dx < 5) ? w1[((oc * 2 + c) * 5 + dy) * 5 + dx] * 0.5f : 0.f;
    Wr1[g] = bf16_split_sel(w, s);
}

// ---------------------------------------------------------------------------
// prep_w3: conv3 weights, k = tap*32 + ic. Wr[(((s*9+ks)*4+mt)*64+lane)*8+j].
// ---------------------------------------------------------------------------
__global__ __launch_bounds__(256) void prep_w3_k(
    const float* __restrict__ w3, unsigned short* __restrict__ Wr)
{
    const int g = blockIdx.x * 256 + threadIdx.x;   // 0..55295 (216 blocks exact)
    const int j = g & 7;
    const int lane = (g >> 3) & 63;
    const int mt = (g >> 9) & 3;
    const int rest = g >> 11;        // 0..26
    const int ks = rest % 9;
    const int s = rest / 9;
    const int oc = mt * 16 + (lane & 15);
    const int ic = (lane >> 4) * 8 + j;
    Wr[g] = bf16_split_sel(w3[(oc * 32 + ic) * 9 + ks], s);
}

// ---------------------------------------------------------------------------
// prep_w2: conv2 weights, tap-pair packing (k = tap_local*16 + ic; tap 9
// padded with exact zeros). Wr2[(((s*5+kp)*2+mt)*64+lane)*8+j].
// ---------------------------------------------------------------------------
__global__ __launch_bounds__(256) void prep_w2_k(
    const float* __restrict__ w2, unsigned short* __restrict__ Wr2)
{
    const int g = blockIdx.x * 256 + threadIdx.x;   // 0..15359 (60 blocks exact)
    const int j = g & 7;
    const int lane = (g >> 3) & 63;
    const int mt = (g >> 9) & 1;
    const int rest = g >> 10;        // 0..14
    const int kp = rest % 5;
    const int s = rest / 5;
    const int q = lane >> 4;
    const int oc = mt * 16 + (lane & 15);
    const int tap = kp * 2 + (q >> 1);
    const int ic = (q & 1) * 8 + j;
    const float w = (tap <= 8) ? w2[(oc * 16 + ic) * 9 + tap] : 0.f;
    Wr2[g] = bf16_split_sel(w, s);
}

// ---------------------------------------------------------------------------
// R11 layer-1: producer-consumer conv+spike (R9-verified) + FUSED pool2.
// The block's 2-row x 8-col strip x 16 oc pools to exactly 1 pool row x 4
// pool cols x 16 c. Pool sources for (ty, tx*4+x') are lanes
// lb + {2x', 2x'+1, 8+2x', 9+2x'} of the SAME wave -> 4 __shfl. Pool
// recurrence runs on lanes with (lane&15)<4 with its own state; values and
// order identical to pool_body (11.0f * byte-sum, chunk-ascending).
// s1 never touches HBM; conv1pc writes pooled s2 directly.
// ---------------------------------------------------------------------------
__device__ __forceinline__ void c1_mfma_chunk(
    const unsigned int* __restrict__ tb, const int* offA, const int* offB,
    const short8* Af, f32x4* acc)
{
    // READ phase: all 32 LDS reads issued before any consumer.
    unsigned int vA[4][4], vB[4][4];   // [ks][t], fully unrolled -> registers
#pragma unroll
    for (int ks = 0; ks < 4; ++ks)
#pragma unroll
        for (int t = 0; t < 4; ++t) {
            vA[ks][t] = tb[t * 72 + offA[ks]];
            vB[ks][t] = tb[t * 72 + offB[ks]];
        }

    // MFMA phase (same ks -> t -> s order/operands as verified kernel).
#pragma unroll
    for (int t = 0; t < 4; ++t) acc[t] = (f32x4){0.f, 0.f, 0.f, 0.f};
#pragma unroll
    for (int ks = 0; ks < 4; ++ks)
#pragma unroll
        for (int t = 0; t < 4; ++t) {
            union { uint4 u; short8 s8; } cv;
            cv.u.x = vA[ks][t]; cv.u.y = vA[ks][t];
            cv.u.z = vB[ks][t]; cv.u.w = vB[ks][t];
#pragma unroll
            for (int s = 0; s < 3; ++s)
                acc[t] = __builtin_amdgcn_mfma_f32_16x16x32_bf16(
                    Af[s * 4 + ks], cv.s8, acc[t], 0, 0, 0);
        }
}

__global__ __launch_bounds__(512, 4) void conv1pc_k(
    const unsigned int* __restrict__ X, const unsigned short* __restrict__ Wr1,
    uchar4* __restrict__ S2, RefK rk)
{
    __shared__ unsigned int tab[2][5 * 288];          // 2 x 5.76 KB
    __shared__ __align__(16) float4 Ulds[2][5 * 256]; // 2 x 20 KB
    const int pg = blockIdx.x;                // 0..63
    const int b = blockIdx.y;                 // 0..7
    const int ty = pg >> 2, tx = pg & 3;      // 2-row strip / 8-col strip
    const int tid = threadIdx.x;              // 0..511 (8 waves)
    const int wv = tid >> 6, lane = tid & 63;
    const bool isConv = (wv >= 4);
    const int q = lane >> 4, n = lane & 15;
    const int py0 = n >> 3, px0 = n & 7;

    // ---- conv-side state (waves 4-7) ----
    short8 Af[12];   // [s][ks]
    int offA[4], offB[4];
    int lidx[2], gof[2];
    unsigned int w0[2], w1[2];
    if (isConv) {
#pragma unroll
        for (int s = 0; s < 3; ++s)
#pragma unroll
            for (int ks = 0; ks < 4; ++ks)
                Af[s * 4 + ks] = *(const short8*)(Wr1 + (((s * 4 + ks) * 64 + lane) * 8));
#pragma unroll
        for (int ks = 0; ks < 4; ++ks) {
            const int sA = ks * 8 + q * 2, sB = sA + 1;
            const int dyA = sA / 6, dxA = sA - dyA * 6;
            const int dyB = sB / 6, dxB = sB - dyB * 6;
            offA[ks] = min(py0 + dyA, 5) * 12 + min(px0 + dxA, 11);
            offB[ks] = min(py0 + dyB, 5) * 12 + min(px0 + dxB, 11);
        }
        // staging geometry: 5*72 = 360 entries over 256 conv threads, 2 rounds
        const int tid2 = tid - 256;
#pragma unroll
        for (int i = 0; i < 2; ++i) {
            const int e = i * 256 + tid2;
            if (e < 360) {
                const int chl = e / 72, site = e - chl * 72;
                const int r = site / 12, cc = site - r * 12;
                const int gy = ty * 2 - 1 + r, gx = tx * 8 - 1 + cc;
                lidx[i] = chl * 288 + site;
                gof[i] = (((unsigned)gy < 34u) && ((unsigned)gx < 34u))
                       ? (chl * 18496 + (b * 2) * 1156 + gy * 34 + gx) : -1;
            } else { lidx[i] = -1; gof[i] = -1; }
        }
        // window-0 loads + unpack into tab[0]
#pragma unroll
        for (int i = 0; i < 2; ++i) {
            if (gof[i] >= 0) { w0[i] = X[gof[i]]; w1[i] = X[gof[i] + 1156]; }
            else { w0[i] = 0u; w1[i] = 0u; }
        }
#pragma unroll
        for (int i = 0; i < 2; ++i) {
            if (lidx[i] >= 0) {
#pragma unroll
                for (int t = 0; t < 4; ++t)
                    tab[0][lidx[i] + t * 72] =
                        ((w0[i] >> (8 * t)) & 0xFFu) * 0x3F80u
                        | ((((w1[i] >> (8 * t)) & 0xFFu) * 0x3F80u) << 16);
            }
        }
    }

    // ---- spike-side state (waves 0-3): ONE s1 neuron per thread + pool ----
    float buf[10], buf2[10];
#pragma unroll
    for (int r = 0; r < 10; ++r) { buf[r] = 0.f; buf2[r] = 0.f; }
    const int s_oc = (tid & 255) >> 4;
    const int lb = lane & 48;                  // 16-lane oc-group base
    const int xq = lane & 3;                   // pool x' (lanes with lane&15<4)
    const size_t s2base = ((size_t)(b * 16 + s_oc) * 16 + ty) * 16 + (tx * 4 + (lane & 15));

    auto spike_pool = [&](int ch, const float4& u) {
        union { uchar4 c; int i; } o;
        o.c.x = spike_step(u.x, buf, rk);
        o.c.y = spike_step(u.y, buf, rk);
        o.c.z = spike_step(u.z, buf, rk);
        o.c.w = spike_step(u.w, buf, rk);
        const int g0 = __shfl(o.i, lb + 2 * xq, 64);
        const int g1 = __shfl(o.i, lb + 2 * xq + 1, 64);
        const int g2 = __shfl(o.i, lb + 8 + 2 * xq, 64);
        const int g3 = __shfl(o.i, lb + 9 + 2 * xq, 64);
        if ((lane & 15) < 4) {
            uchar4 po;
            po.x = spike_step(11.0f * (float)psum4(g0, g1, g2, g3, 0), buf2, rk);
            po.y = spike_step(11.0f * (float)psum4(g0, g1, g2, g3, 8), buf2, rk);
            po.z = spike_step(11.0f * (float)psum4(g0, g1, g2, g3, 16), buf2, rk);
            po.w = spike_step(11.0f * (float)psum4(g0, g1, g2, g3, 24), buf2, rk);
            S2[(size_t)ch * 32768 + s2base] = po;
        }
    };

    __syncthreads();   // tab[0] ready

    for (int w = 0; w < 15; ++w) {
        const int cb = w & 1;
        if (isConv) {
            if (w < 14) {  // issue next window's loads; latency hides under conv
                const unsigned int* Xs = X + (size_t)(w + 1) * (5 * 18496);
#pragma unroll
                for (int i = 0; i < 2; ++i) {
                    if (gof[i] >= 0) { w0[i] = Xs[gof[i]]; w1[i] = Xs[gof[i] + 1156]; }
                }
            }
            // conv window w: waves 4-7 own chunks (wv-4), (wv-4)+4
            for (int k = wv - 4; k < 5; k += 4) {
                f32x4 acc[4];
                c1_mfma_chunk(&tab[cb][k * 288], offA, offB, Af, acc);
#pragma unroll
                for (int rr = 0; rr < 4; ++rr)
                    Ulds[cb][k * 256 + (q * 4 + rr) * 16 + n] =
                        make_float4(acc[0][rr], acc[1][rr], acc[2][rr], acc[3][rr]);
            }
            if (w < 14) {  // unpack next window into the other tab buffer
#pragma unroll
                for (int i = 0; i < 2; ++i) {
                    if (lidx[i] >= 0) {
#pragma unroll
                        for (int t = 0; t < 4; ++t)
                            tab[cb ^ 1][lidx[i] + t * 72] =
                                ((w0[i] >> (8 * t)) & 0xFFu) * 0x3F80u
                                | ((((w1[i] >> (8 * t)) & 0xFFu) * 0x3F80u) << 16);
                    }
                }
            }
        } else if (w > 0) {
            // spike+pool window w-1 from Ulds[(w-1)&1]
            const int pb = (w - 1) & 1;
            for (int k = 0; k < 5; ++k)
                spike_pool((w - 1) * 5 + k, Ulds[pb][k * 256 + tid]);
        }
        __syncthreads();
    }
    // epilogue: spike+pool window 14 (in Ulds[14&1 = 0])
    if (!isConv) {
        for (int k = 0; k < 5; ++k)
            spike_pool(70 + k, Ulds[0][k * 256 + tid]);
    }
}

// ---------------------------------------------------------------------------
// conv2 via MFMA (R15, verified): [4t][18][18][16ic] u8, tap-pair K-packing.
// ---------------------------------------------------------------------------
__global__ __launch_bounds__(256) void conv2_mfma_k(
    const unsigned int* __restrict__ s2u, const unsigned short* __restrict__ Wr2,
    float4* __restrict__ U, int b0, int nbl)
{
    __shared__ __align__(16) unsigned char pad[4 * 18 * 18 * 16];   // 20736
    const int tc = blockIdx.x;
    const int bl = blockIdx.z;
    const int b = b0 + bl;
    const int tid = threadIdx.x;
    const int wv = tid >> 6, lane = tid & 63;
    const int q = lane >> 4, n = lane & 15;
    const int PLANE_U = nbl * 8192;      // float4 per chunk

    unsigned int* lp = (unsigned int*)pad;
    for (int i = tid; i < 5184; i += 256) lp[i] = 0u;
    __syncthreads();
    const unsigned int* sb = s2u + (size_t)tc * 32768 + b * 4096;
    for (int e = tid; e < 4096; e += 256) {
        const unsigned int v = sb[e];
        const int c = e >> 8, pix = e & 255;
        const int base = (((pix >> 4) + 1) * 18 + ((pix & 15) + 1)) * 16 + c;
        pad[base]         = (unsigned char)(v & 0xFFu);
        pad[5184 + base]  = (unsigned char)((v >> 8) & 0xFFu);
        pad[10368 + base] = (unsigned char)((v >> 16) & 0xFFu);
        pad[15552 + base] = (unsigned char)(v >> 24);
    }
    __syncthreads();

    for (int i = 0; i < 4; ++i) {
        const int r = wv * 4 + i;        // pixel row (N-tile)
        f32x4 acc[2][4];                 // [oc-tile][t]
#pragma unroll
        for (int mt = 0; mt < 2; ++mt)
#pragma unroll
            for (int t = 0; t < 4; ++t) acc[mt][t] = (f32x4){0.f, 0.f, 0.f, 0.f};

        for (int kp = 0; kp < 5; ++kp) {
            short8 Af[6];   // [s][mt]
#pragma unroll
            for (int s = 0; s < 3; ++s)
#pragma unroll
                for (int mt = 0; mt < 2; ++mt)
                    Af[s * 2 + mt] = *(const short8*)(Wr2 + ((((s * 5 + kp) * 2 + mt) * 64 + lane) * 8));
            int tap = kp * 2 + (q >> 1);
            if (tap > 8) tap = 8;        // pad step: A is zero, address just valid
            const int dy = tap / 3, dx = tap % 3;
#pragma unroll
            for (int t = 0; t < 4; ++t) {
                const int off = ((t * 18 + r + dy) * 18 + (n + dx)) * 16 + (q & 1) * 8;
                const short8 Bf = bytes_to_bf16x8(*(const uint2*)(pad + off));
#pragma unroll
                for (int s = 0; s < 3; ++s)
#pragma unroll
                    for (int mt = 0; mt < 2; ++mt)
                        acc[mt][t] = __builtin_amdgcn_mfma_f32_16x16x32_bf16(
                            Af[s * 2 + mt], Bf, acc[mt][t], 0, 0, 0);
            }
        }

        const size_t ub = (size_t)tc * PLANE_U;
#pragma unroll
        for (int mt = 0; mt < 2; ++mt)
#pragma unroll
            for (int rr = 0; rr < 4; ++rr) {
                const int oc = mt * 16 + q * 4 + rr;
                const int nb = (bl * 32 + oc) * 256 + r * 16 + n;
                U[ub + nb] = make_float4(acc[mt][0][rr], acc[mt][1][rr], acc[mt][2][rr], acc[mt][3][rr]);
            }
    }
}

// ---------------------------------------------------------------------------
// conv3 via MFMA (R14, verified): [4t][10][10][32ic] u8 tile, k = tap*32+ic.
// ---------------------------------------------------------------------------
__global__ __launch_bounds__(256) void conv3_mfma_k(
    const unsigned int* __restrict__ s4u, const unsigned short* __restrict__ Wr,
    float4* __restrict__ U)
{
    __shared__ __align__(16) unsigned char pad[12800];   // [t][row10][col10][ic32]
    const int tc = blockIdx.x;
    const int bl = blockIdx.z;
    const int tid = threadIdx.x;
    const int wv = tid >> 6, lane = tid & 63;
    const int q = lane >> 4, n = lane & 15;

    unsigned int* lp = (unsigned int*)pad;
    for (int i = tid; i < 3200; i += 256) lp[i] = 0u;
    __syncthreads();
    const unsigned int* sb = s4u + (size_t)tc * 16384 + bl * 2048;
    for (int e = tid; e < 2048; e += 256) {
        const unsigned int v = sb[e];
        const int c = e >> 6, pix = e & 63;
        const int base = (((pix >> 3) + 1) * 10 + ((pix & 7) + 1)) * 32 + c;
        pad[base]        = (unsigned char)(v & 0xFFu);
        pad[3200 + base] = (unsigned char)((v >> 8) & 0xFFu);
        pad[6400 + base] = (unsigned char)((v >> 16) & 0xFFu);
        pad[9600 + base] = (unsigned char)(v >> 24);
    }
    __syncthreads();

    const int pixel = wv * 16 + n;
    const int py0 = pixel >> 3, px0 = pixel & 7;

    f32x4 acc[4][4];   // [oc-tile][t]
#pragma unroll
    for (int mt = 0; mt < 4; ++mt)
#pragma unroll
        for (int t = 0; t < 4; ++t) acc[mt][t] = (f32x4){0.f, 0.f, 0.f, 0.f};

    for (int ks = 0; ks < 9; ++ks) {
        const int dy = ks / 3, dx = ks % 3;
        short8 Af[12];
#pragma unroll
        for (int s = 0; s < 3; ++s)
#pragma unroll
            for (int mt = 0; mt < 4; ++mt)
                Af[s * 4 + mt] = *(const short8*)(Wr + ((((s * 9 + ks) * 4 + mt) * 64 + lane) * 8));
#pragma unroll
        for (int t = 0; t < 4; ++t) {
            const int off = ((t * 10 + py0 + dy) * 10 + (px0 + dx)) * 32 + q * 8;
            const short8 Bf = bytes_to_bf16x8(*(const uint2*)(pad + off));
#pragma unroll
            for (int s = 0; s < 3; ++s)
#pragma unroll
                for (int mt = 0; mt < 4; ++mt)
                    acc[mt][t] = __builtin_amdgcn_mfma_f32_16x16x32_bf16(
                        Af[s * 4 + mt], Bf, acc[mt][t], 0, 0, 0);
        }
    }

    const size_t ub = (size_t)tc * 32768 + (size_t)bl * 4096;
#pragma unroll
    for (int mt = 0; mt < 4; ++mt)
#pragma unroll
        for (int r = 0; r < 4; ++r) {
            const int oc = mt * 16 + q * 4 + r;
            const int nb = oc * 64 + wv * 16 + n;
            U[ub + nb] = make_float4(acc[mt][0][r], acc[mt][1][r], acc[mt][2][r], acc[mt][3][r]);
        }
}

// ---------------------------------------------------------------------------
// spike2p: layer-2 spike scan + FUSED pool4. Each 64-thread block covers 4
// consecutive rows x 16 cols of one (b, oc) = 2 pool rows x 8 pool cols.
// Sources for pool (py, px) are lanes 32*py+2*px {+0,+1,+16,+17} (same wave).
// Writes ONLY pooled s4 (s3 never materialized). Values/order identical to
// spike_body + pool_body (bit-exact).
// ---------------------------------------------------------------------------
__global__ __launch_bounds__(64) void spike2p_k(
    const float4* __restrict__ U, uchar4* __restrict__ S4,
    int nneur, int b0, RefK rk)
{
    const int lane = threadIdx.x;
    const int n = blockIdx.x * 64 + lane;
    const float4* up = U + n;
    float buf[10], buf2[10];
#pragma unroll
    for (int r = 0; r < 10; ++r) { buf[r] = 0.f; buf2[r] = 0.f; }

    // neuron decode: local layout [bl][oc][y][x], x fastest (16), y (16)
    const int bl = n >> 13, oc = (n >> 8) & 31, y = (n >> 4) & 15;
    const int b = b0 + bl;
    const int y0 = y & ~3;                 // block base row (blocks are 4-row aligned)
    const int p = lane & 15, ppy = p >> 3, ppx = p & 7;
    const int sB = 32 * ppy + 2 * ppx;     // source lane base
    const size_t s4base = (size_t)(b * 32 + oc) * 64 + ((y0 >> 1) + ppy) * 8 + ppx;

    auto step_pool = [&](int ch, const float4& cur) {
        union { uchar4 c; int i; } o;
        o.c.x = spike_step(cur.x, buf, rk);
        o.c.y = spike_step(cur.y, buf, rk);
        o.c.z = spike_step(cur.z, buf, rk);
        o.c.w = spike_step(cur.w, buf, rk);
        const int g0 = __shfl(o.i, sB, 64);
        const int g1 = __shfl(o.i, sB + 1, 64);
        const int g2 = __shfl(o.i, sB + 16, 64);
        const int g3 = __shfl(o.i, sB + 17, 64);
        if (lane < 16) {
            uchar4 po;
            po.x = spike_step(11.0f * (float)psum4(g0, g1, g2, g3, 0), buf2, rk);
            po.y = spike_step(11.0f * (float)psum4(g0, g1, g2, g3, 8), buf2, rk);
            po.z = spike_step(11.0f * (float)psum4(g0, g1, g2, g3, 16), buf2, rk);
            po.w = spike_step(11.0f * (float)psum4(g0, g1, g2, g3, 24), buf2, rk);
            S4[(size_t)ch * 16384 + s4base] = po;
        }
    };

    float4 ring[8];
#pragma unroll
    for (int r = 0; r < 8; ++r) ring[r] = up[(size_t)r * nneur];

#pragma unroll 8
    for (int ch = 0; ch < 72; ++ch) {
        const float4 cur = ring[ch & 7];
        const int pf = (ch + 8 < NCHUNK) ? ch + 8 : NCHUNK - 1;
        ring[ch & 7] = up[(size_t)pf * nneur];
        step_pool(ch, cur);
    }
#pragma unroll
    for (int ch = 72; ch < NCHUNK; ++ch) {
        step_pool(ch, ring[ch & 7]);
    }
}

// ---------------------------------------------------------------------------
// spike body (layer 3): per-neuron scan. float4 per chunk in, uchar4 out.
// ---------------------------------------------------------------------------
__global__ __launch_bounds__(64) void spike3_k(
    const float4* __restrict__ U, uchar4* __restrict__ S,
    int nneur, int sstride, int soff, RefK rk)
{
    const int n = blockIdx.x * 64 + threadIdx.x;
    const float4* up = U + n;
    uchar4* sp = S + soff + n;
    float buf[10];
#pragma unroll
    for (int r = 0; r < 10; ++r) buf[r] = 0.f;

    float4 ring[8];
#pragma unroll
    for (int r = 0; r < 8; ++r) ring[r] = up[(size_t)r * nneur];

#pragma unroll 8
    for (int ch = 0; ch < 72; ++ch) {
        const float4 cur = ring[ch & 7];
        const int pf = (ch + 8 < NCHUNK) ? ch + 8 : NCHUNK - 1;
        ring[ch & 7] = up[(size_t)pf * nneur];
        uchar4 o;
        o.x = spike_step(cur.x, buf, rk);
        o.y = spike_step(cur.y, buf, rk);
        o.z = spike_step(cur.z, buf, rk);
        o.w = spike_step(cur.w, buf, rk);
        sp[(size_t)ch * sstride] = o;
    }
#pragma unroll
    for (int ch = 72; ch < NCHUNK; ++ch) {
        const float4 cur = ring[ch & 7];
        uchar4 o;
        o.x = spike_step(cur.x, buf, rk);
        o.y = spike_step(cur.y, buf, rk);
        o.z = spike_step(cur.z, buf, rk);
        o.w = spike_step(cur.w, buf, rk);
        sp[(size_t)ch * sstride] = o;
    }
}

// ---------------------------------------------------------------------------
// dense u (R0-verified): one block per (tc, o, b).
// U6[tc][b*10+o][4] = sum_site wfc[o,site] * s5[tc][b*4096+site][4]
// ---------------------------------------------------------------------------
__global__ __launch_bounds__(64) void dense_k(
    const uchar4* __restrict__ S5, const float* __restrict__ WFC,
    float4* __restrict__ U6)
{
    const int tc = blockIdx.x, o = blockIdx.y, b = blockIdx.z;
    const int lane = threadIdx.x;
    float a0 = 0.f, a1 = 0.f, a2 = 0.f, a3 = 0.f;
    const uchar4* sb = S5 + (size_t)tc * 32768 + b * 4096;
    const float* wb = WFC + o * 4096;
    for (int i = 0; i < 64; ++i) {
        const int site = i * 64 + lane;
        const uchar4 s = sb[site];
        const float w = wb[site];
        a0 = fmaf(w, (float)s.x, a0);
        a1 = fmaf(w, (float)s.y, a1);
        a2 = fmaf(w, (float)s.z, a2);
        a3 = fmaf(w, (float)s.w, a3);
    }
#pragma unroll
    for (int m = 1; m < 64; m <<= 1) {
        a0 += __shfl_xor(a0, m, 64);
        a1 += __shfl_xor(a1, m, 64);
        a2 += __shfl_xor(a2, m, 64);
        a3 += __shfl_xor(a3, m, 64);
    }
    if (lane == 0)
        U6[(size_t)tc * 80 + b * 10 + o] = make_float4(a0, a1, a2, a3);
}

// final spike over 80 neurons; float4 chunks in, [n][t] fp32 out.
__global__ __launch_bounds__(128) void spike6_k(
    const float4* __restrict__ U6, float* __restrict__ Out, RefK rk)
{
    const int n = threadIdx.x;
    if (n >= 80) return;
    const float4* up = U6 + n;
    float* op = Out + (size_t)n * T_SAMPLE;
    float buf[10];
#pragma unroll
    for (int r = 0; r < 10; ++r) buf[r] = 0.f;

    float4 ring[8];
#pragma unroll
    for (int r = 0; r < 8; ++r) ring[r] = up[(size_t)r * 80];

#pragma unroll 8
    for (int ch = 0; ch < 72; ++ch) {
        const float4 cur = ring[ch & 7];
        const int pf = (ch + 8 < NCHUNK) ? ch + 8 : NCHUNK - 1;
        ring[ch & 7] = up[(size_t)pf * 80];
        float4 o;
        o.x = (float)spike_step(cur.x, buf, rk);
        o.y = (float)spike_step(cur.y, buf, rk);
        o.z = (float)spike_step(cur.z, buf, rk);
        o.w = (float)spike_step(cur.w, buf, rk);
        *(float4*)(op + ch * 4) = o;
    }
#pragma unroll
    for (int ch = 72; ch < NCHUNK; ++ch) {
        const float4 cur = ring[ch & 7];
        float4 o;
        o.x = (float)spike_step(cur.x, buf, rk);
        o.y = (float)spike_step(cur.y, buf, rk);
        o.z = (float)spike_step(cur.z, buf, rk);
        o.w = (float)spike_step(cur.w, buf, rk);
        *(float4*)(op + ch * 4) = o;
    }
}

extern "C" void kernel_launch(void* const* d_in, const int* in_sizes, int n_in,
                              void* d_out, int out_size, void* d_ws, size_t ws_size,
                              hipStream_t stream)
{
    const float* spikeIn = (const float*)d_in[0];  // [8,2,34,34,300]
    const float* w1 = (const float*)d_in[1];       // [16,2,5,5]
    const float* w2 = (const float*)d_in[2];       // [32,16,3,3]
    const float* w3 = (const float*)d_in[3];       // [64,32,3,3]
    const float* wfc = (const float*)d_in[4];      // [10,64,8,8]
    float* out = (float*)d_out;                    // [8,10,1,1,300]

    RefK rk;
    for (int t = 1; t <= 10; ++t)
        rk.v[t - 1] = (float)(-20.0 * (double)t * std::exp(1.0 - (double)t));

    // Workspace (pools fused -> s1/s3 never materialized):
    //   U region: big tier 78.6 MB (conv2 nbl2=8) else 39.3 MB (nbl2=4).
    //   A region 39.3 MB: s2 at A+0 (9.8 MB, written by conv1pc);
    //     s5 at A+0 (9.8 MB, after s2 dead post-conv2);
    //     Wr/Wr2 at A+20 MB (disjoint from s2/s5).
    //   B region 9.8 MB: X at B+0 (5.55 MB, dead after conv1pc);
    //     Wr1 at B+5.57 MB; s4 at B+0 (4.9 MB, after X dead).
    const size_t A_BYTES = 39321600;
    const size_t B_BYTES = 9830400;
    const size_t U6_BYTES = 96000;
    const size_t U_BIG = 78643200, U_SMALL = 39321600;
    const size_t TAIL = A_BYTES + B_BYTES + U6_BYTES;
    const bool big = ws_size >= U_BIG + TAIL;
    const size_t U_BYTES = big ? U_BIG : U_SMALL;

    char* ws = (char*)d_ws;
    float4* U = (float4*)ws;
    char* Ab = ws + U_BYTES;
    char* Bb = ws + U_BYTES + A_BYTES;
    float4* U6 = (float4*)(ws + U_BYTES + A_BYTES + B_BYTES);
    unsigned short* Wr = (unsigned short*)(Ab + 20971520);            // A+20MB
    unsigned short* Wr2 = (unsigned short*)(Ab + 20971520 + 131072);  // A+20MB+128K
    unsigned short* Wr1 = (unsigned short*)(Bb + 5570560);            // B+5.57MB (past X)

    unsigned int* X = (unsigned int*)Bb;   // 5.549 MB; dead after conv1pc
    uchar4* s2 = (uchar4*)Ab;              // 9.83 MB, pooled layer-1 spikes
    uchar4* s4 = (uchar4*)Bb;              // 4.92 MB, pooled layer-2 spikes
    uchar4* s5 = (uchar4*)Ab;              // 9.83 MB (s2 dead after conv2)

    // ---- input transpose + conv1 weight prep ----
    transpose_in_k<<<18496 / 16, 256, 0, stream>>>(spikeIn, X);
    prep_w1_k<<<24, 256, 0, stream>>>(w1, Wr1);

    // ---- layer 1: producer-consumer conv+spike + fused pool2 -> s2 ----
    {
        dim3 g1(64, 8);   // (pixel-group 2x8, batch) = 512 blocks x 512 thr
        conv1pc_k<<<g1, 512, 0, stream>>>(X, Wr1, s2, rk);
    }
    // ---- conv2/conv3 weight preps ----
    prep_w2_k<<<60, 256, 0, stream>>>(w2, Wr2);
    prep_w3_k<<<216, 256, 0, stream>>>(w3, Wr);
    // ---- layer 2: MFMA conv(16->32, k3) + spike + fused pool4 -> s4 ----
    const int nbl2 = big ? 8 : 4;
    for (int b0 = 0; b0 < 8; b0 += nbl2) {
        dim3 g2(NCHUNK, 1, nbl2);
        conv2_mfma_k<<<g2, 256, 0, stream>>>((const unsigned int*)s2, Wr2, U, b0, nbl2);
        const int nn = nbl2 * 8192;
        spike2p_k<<<nn / 64, 64, 0, stream>>>(U, s4, nn, b0, rk);
    }
    // ---- layer 3: MFMA conv(32->64, k3) + spike, full batch ----
    {
        dim3 g3(NCHUNK, 1, 8);   // (tc, -, bl): 600 blocks
        conv3_mfma_k<<<g3, 256, 0, stream>>>((const unsigned int*)s4, Wr, U);
        spike3_k<<<32768 / 64, 64, 0, stream>>>(U, s5, 32768, 32768, 0, rk);
    }
    // ---- dense (R0 form: one block per (tc,o,b)) + final spike ----
    {
        dim3 g6(NCHUNK, 10, 8);
        dense_k<<<g6, 64, 0, stream>>>(s5, wfc, U6);
    }
    spike6_k<<<1, 128, 0, stream>>>(U6, out, rk);
}

// Round 12
// 249.251 us; speedup vs baseline: 1.0701x; 1.0701x over previous
//
#include <hip/hip_runtime.h>
#include <hip/hip_bf16.h>
#include <cmath>

#define T_SAMPLE 300
#define NCHUNK 75   // T / 4

typedef __attribute__((ext_vector_type(8))) short short8;
typedef __attribute__((ext_vector_type(4))) float f32x4;

struct RefK { float v[10]; };

// One step of the SLAYER spike recurrence. buf[0..9] = pending refractory.
__device__ __forceinline__ unsigned char spike_step(float u, float* buf, const RefK& rk) {
    const float um = u + buf[0];
    const bool fire = um >= 10.0f;
    const float ev = fire ? 1.0f : 0.0f;
#pragma unroll
    for (int r = 0; r < 9; ++r) buf[r] = fmaf(ev, rk.v[r], buf[r + 1]);
    buf[9] = ev * rk.v[9];
    return fire ? (unsigned char)1 : (unsigned char)0;
}

// byte->bf16 pack: 8 spike bytes (0/1) -> short8 of bf16 (1.0 = 0x3F80)
__device__ __forceinline__ short8 bytes_to_bf16x8(uint2 w8) {
    union { uint4 u; short8 s8; } cv;
    cv.u.x = (w8.x & 0xFFu) * 0x3F80u | ((((w8.x >> 8) & 0xFFu) * 0x3F80u) << 16);
    cv.u.y = ((w8.x >> 16) & 0xFFu) * 0x3F80u | ((((w8.x >> 24) & 0xFFu) * 0x3F80u) << 16);
    cv.u.z = (w8.y & 0xFFu) * 0x3F80u | ((((w8.y >> 8) & 0xFFu) * 0x3F80u) << 16);
    cv.u.w = ((w8.y >> 16) & 0xFFu) * 0x3F80u | ((((w8.y >> 24) & 0xFFu) * 0x3F80u) << 16);
    return cv.s8;
}

// 3-way exact bf16 split selector (24 mantissa bits = 3x8; residual 0)
__device__ __forceinline__ unsigned short bf16_split_sel(float w, int s) {
    __hip_bfloat16 hb = __float2bfloat16(w);
    const float hf = __bfloat162float(hb);
    __hip_bfloat16 mb = __float2bfloat16(w - hf);
    const float mf = __bfloat162float(mb);
    __hip_bfloat16 lb = __float2bfloat16(w - hf - mf);
    __hip_bfloat16 sel = (s == 0) ? hb : ((s == 1) ? mb : lb);
    return *(unsigned short*)&sel;
}

// ---------------------------------------------------------------------------
// transpose input [B,2,34,34,T] f32 ({0,1}) -> X[tchunk][n][4] u8, n = b,c,y,x
// ---------------------------------------------------------------------------
__global__ __launch_bounds__(256) void transpose_in_k(
    const float* __restrict__ In, unsigned int* __restrict__ X)
{
    __shared__ unsigned int lds[16 * NCHUNK];
    const int blk = blockIdx.x;          // 1156 blocks x 16 neurons
    const int tn = threadIdx.x >> 4;     // 0..15 neuron
    const int tq = threadIdx.x & 15;     // 0..15 t-group
    const size_t n = (size_t)blk * 16 + tn;
#pragma unroll
    for (int p = 0; p < 5; ++p) {
        const int ch = p * 16 + tq;
        if (ch < NCHUNK) {
            const float4 v = *(const float4*)(In + n * T_SAMPLE + ch * 4);
            unsigned int u = (v.x != 0.f ? 1u : 0u) | (v.y != 0.f ? 0x100u : 0u) |
                             (v.z != 0.f ? 0x10000u : 0u) | (v.w != 0.f ? 0x1000000u : 0u);
            lds[tn * NCHUNK + ch] = u;
        }
    }
    __syncthreads();
    for (int idx = threadIdx.x; idx < 16 * NCHUNK; idx += 256) {
        const int ch = idx >> 4, t2 = idx & 15;
        X[(size_t)ch * 18496 + blk * 16 + t2] = lds[t2 * NCHUNK + ch];
    }
}

// ---------------------------------------------------------------------------
// prep_w1: conv1 weights for MFMA, c-DUPLICATED packing. k = slot*4 + c2,
// slot = dy*6+dx (dx=5 and slot>=30 zero), c = c2&1, weight = w/2 (dup x2).
// Wr1[((s*4+ks)*64+lane)*8+j]: oc = lane&15, k = ks*32 + (lane>>4)*8 + j.
// ---------------------------------------------------------------------------
__global__ __launch_bounds__(256) void prep_w1_k(
    const float* __restrict__ w1, unsigned short* __restrict__ Wr1)
{
    const int g = blockIdx.x * 256 + threadIdx.x;   // 0..6143 (24 blocks exact)
    const int j = g & 7;
    const int lane = (g >> 3) & 63;
    const int ks = (g >> 9) & 3;
    const int s = g >> 11;               // 0..2
    const int q = lane >> 4;
    const int oc = lane & 15;
    const int kg = ks * 32 + q * 8 + j;
    const int slot = kg >> 2, c = kg & 1;
    const int dy = slot / 6, dx = slot % 6;
    const float w = (dy < 5 && dx < 5) ? w1[((oc * 2 + c) * 5 + dy) * 5 + dx] * 0.5f : 0.f;
    Wr1[g] = bf16_split_sel(w, s);
}

// ---------------------------------------------------------------------------
// prep_w3: conv3 weights, k = tap*32 + ic. Wr[(((s*9+ks)*4+mt)*64+lane)*8+j].
// ---------------------------------------------------------------------------
__global__ __launch_bounds__(256) void prep_w3_k(
    const float* __restrict__ w3, unsigned short* __restrict__ Wr)
{
    const int g = blockIdx.x * 256 + threadIdx.x;   // 0..55295 (216 blocks exact)
    const int j = g & 7;
    const int lane = (g >> 3) & 63;
    const int mt = (g >> 9) & 3;
    const int rest = g >> 11;        // 0..26
    const int ks = rest % 9;
    const int s = rest / 9;
    const int oc = mt * 16 + (lane & 15);
    const int ic = (lane >> 4) * 8 + j;
    Wr[g] = bf16_split_sel(w3[(oc * 32 + ic) * 9 + ks], s);
}

// ---------------------------------------------------------------------------
// prep_w2: conv2 weights, tap-pair packing (k = tap_local*16 + ic; tap 9
// padded with exact zeros). Wr2[(((s*5+kp)*2+mt)*64+lane)*8+j].
// ---------------------------------------------------------------------------
__global__ __launch_bounds__(256) void prep_w2_k(
    const float* __restrict__ w2, unsigned short* __restrict__ Wr2)
{
    const int g = blockIdx.x * 256 + threadIdx.x;   // 0..15359 (60 blocks exact)
    const int j = g & 7;
    const int lane = (g >> 3) & 63;
    const int mt = (g >> 9) & 1;
    const int rest = g >> 10;        // 0..14
    const int kp = rest % 5;
    const int s = rest / 5;
    const int q = lane >> 4;
    const int oc = mt * 16 + (lane & 15);
    const int tap = kp * 2 + (q >> 1);
    const int ic = (q & 1) * 8 + j;
    const float w = (tap <= 8) ? w2[(oc * 16 + ic) * 9 + tap] : 0.f;
    Wr2[g] = bf16_split_sel(w, s);
}

// ---------------------------------------------------------------------------
// R12 layer-1: producer-consumer conv+spike (R9/R10-verified structure),
// WINDOW = 4 chunks: each conv wave owns exactly ONE chunk per window
// (balanced; was 2/1/1/1 with window 5) and LDS drops 52.7 -> 42.0 KB ->
// 3 blocks/CU (24 waves, 6/SIMD). 19 windows, last = 3 chunks (wave 7 idle
// once; tail prefetch reads past X stay inside the B region - harmless,
// values unused). Conv chunk order is irrelevant (chunks independent);
// spike scan order and all arithmetic identical to R10 (absmax 0.0).
// ---------------------------------------------------------------------------
__device__ __forceinline__ void c1_mfma_chunk(
    const unsigned int* __restrict__ tb, const int* offA, const int* offB,
    const short8* Af, f32x4* acc)
{
    // READ phase: all 32 LDS reads issued before any consumer.
    unsigned int vA[4][4], vB[4][4];   // [ks][t], fully unrolled -> registers
#pragma unroll
    for (int ks = 0; ks < 4; ++ks)
#pragma unroll
        for (int t = 0; t < 4; ++t) {
            vA[ks][t] = tb[t * 72 + offA[ks]];
            vB[ks][t] = tb[t * 72 + offB[ks]];
        }

    // MFMA phase (same ks -> t -> s order/operands as verified kernel).
#pragma unroll
    for (int t = 0; t < 4; ++t) acc[t] = (f32x4){0.f, 0.f, 0.f, 0.f};
#pragma unroll
    for (int ks = 0; ks < 4; ++ks)
#pragma unroll
        for (int t = 0; t < 4; ++t) {
            union { uint4 u; short8 s8; } cv;
            cv.u.x = vA[ks][t]; cv.u.y = vA[ks][t];
            cv.u.z = vB[ks][t]; cv.u.w = vB[ks][t];
#pragma unroll
            for (int s = 0; s < 3; ++s)
                acc[t] = __builtin_amdgcn_mfma_f32_16x16x32_bf16(
                    Af[s * 4 + ks], cv.s8, acc[t], 0, 0, 0);
        }
}

__global__ __launch_bounds__(512, 4) void conv1pc_k(
    const unsigned int* __restrict__ X, const unsigned short* __restrict__ Wr1,
    uchar4* __restrict__ S1, RefK rk)
{
    __shared__ unsigned int tab[2][4 * 288];          // 2 x 4.5 KB
    __shared__ __align__(16) float4 Ulds[2][4 * 256]; // 2 x 16 KB
    const int pg = blockIdx.x;                // 0..63
    const int b = blockIdx.y;                 // 0..7
    const int ty = pg >> 2, tx = pg & 3;      // 2-row strip / 8-col strip
    const int tid = threadIdx.x;              // 0..511 (8 waves)
    const int wv = tid >> 6, lane = tid & 63;
    const bool isConv = (wv >= 4);
    const int q = lane >> 4, n = lane & 15;
    const int py0 = n >> 3, px0 = n & 7;

    // ---- conv-side state (waves 4-7) ----
    short8 Af[12];   // [s][ks]
    int offA[4], offB[4];
    int lidx[2], gof[2];
    unsigned int w0[2], w1[2];
    if (isConv) {
#pragma unroll
        for (int s = 0; s < 3; ++s)
#pragma unroll
            for (int ks = 0; ks < 4; ++ks)
                Af[s * 4 + ks] = *(const short8*)(Wr1 + (((s * 4 + ks) * 64 + lane) * 8));
#pragma unroll
        for (int ks = 0; ks < 4; ++ks) {
            const int sA = ks * 8 + q * 2, sB = sA + 1;
            const int dyA = sA / 6, dxA = sA - dyA * 6;
            const int dyB = sB / 6, dxB = sB - dyB * 6;
            offA[ks] = min(py0 + dyA, 5) * 12 + min(px0 + dxA, 11);
            offB[ks] = min(py0 + dyB, 5) * 12 + min(px0 + dxB, 11);
        }
        // staging geometry: 4*72 = 288 entries over 256 conv threads, 2 rounds
        const int tid2 = tid - 256;
#pragma unroll
        for (int i = 0; i < 2; ++i) {
            const int e = i * 256 + tid2;
            if (e < 288) {
                const int chl = e / 72, site = e - chl * 72;
                const int r = site / 12, cc = site - r * 12;
                const int gy = ty * 2 - 1 + r, gx = tx * 8 - 1 + cc;
                lidx[i] = chl * 288 + site;
                gof[i] = (((unsigned)gy < 34u) && ((unsigned)gx < 34u))
                       ? (chl * 18496 + (b * 2) * 1156 + gy * 34 + gx) : -1;
            } else { lidx[i] = -1; gof[i] = -1; }
        }
        // window-0 loads + unpack into tab[0]
#pragma unroll
        for (int i = 0; i < 2; ++i) {
            if (gof[i] >= 0) { w0[i] = X[gof[i]]; w1[i] = X[gof[i] + 1156]; }
            else { w0[i] = 0u; w1[i] = 0u; }
        }
#pragma unroll
        for (int i = 0; i < 2; ++i) {
            if (lidx[i] >= 0) {
#pragma unroll
                for (int t = 0; t < 4; ++t)
                    tab[0][lidx[i] + t * 72] =
                        ((w0[i] >> (8 * t)) & 0xFFu) * 0x3F80u
                        | ((((w1[i] >> (8 * t)) & 0xFFu) * 0x3F80u) << 16);
            }
        }
    }

    // ---- spike-side state (waves 0-3): ONE neuron per thread ----
    float buf[10];
#pragma unroll
    for (int r = 0; r < 10; ++r) buf[r] = 0.f;
    const int s_oc = (tid & 255) >> 4, s_n = tid & 15;
    const int nb0 = (b * 16 + s_oc) * 1024 + (ty * 2 + (s_n >> 3)) * 32 + tx * 8 + (s_n & 7);

    __syncthreads();   // tab[0] ready

    for (int w = 0; w < 19; ++w) {
        const int cb = w & 1;
        if (isConv) {
            if (w < 18) {  // issue next window's loads; latency hides under conv
                const unsigned int* Xs = X + (size_t)(w + 1) * (4 * 18496);
#pragma unroll
                for (int i = 0; i < 2; ++i) {
                    if (gof[i] >= 0) { w0[i] = Xs[gof[i]]; w1[i] = Xs[gof[i] + 1156]; }
                }
            }
            // conv window w: wave (wv-4) owns exactly chunk (wv-4)
            const int CW = (w == 18) ? 3 : 4;
            const int k = wv - 4;
            if (k < CW) {
                f32x4 acc[4];
                c1_mfma_chunk(&tab[cb][k * 288], offA, offB, Af, acc);
#pragma unroll
                for (int rr = 0; rr < 4; ++rr)
                    Ulds[cb][k * 256 + (q * 4 + rr) * 16 + n] =
                        make_float4(acc[0][rr], acc[1][rr], acc[2][rr], acc[3][rr]);
            }
            if (w < 18) {  // unpack next window into the other tab buffer
#pragma unroll
                for (int i = 0; i < 2; ++i) {
                    if (lidx[i] >= 0) {
#pragma unroll
                        for (int t = 0; t < 4; ++t)
                            tab[cb ^ 1][lidx[i] + t * 72] =
                                ((w0[i] >> (8 * t)) & 0xFFu) * 0x3F80u
                                | ((((w1[i] >> (8 * t)) & 0xFFu) * 0x3F80u) << 16);
                    }
                }
            }
        } else if (w > 0) {
            // spike window w-1 (always 4 chunks; w-1 <= 17 here)
            const int pb = (w - 1) & 1;
            for (int k = 0; k < 4; ++k) {
                const float4 u = Ulds[pb][k * 256 + tid];
                uchar4 o;
                o.x = spike_step(u.x, buf, rk);
                o.y = spike_step(u.y, buf, rk);
                o.z = spike_step(u.z, buf, rk);
                o.w = spike_step(u.w, buf, rk);
                S1[(size_t)((w - 1) * 4 + k) * 131072 + nb0] = o;
            }
        }
        __syncthreads();
    }
    // epilogue: spike window 18 (3 chunks, in Ulds[18&1 = 0])
    if (!isConv) {
        for (int k = 0; k < 3; ++k) {
            const float4 u = Ulds[0][k * 256 + tid];
            uchar4 o;
            o.x = spike_step(u.x, buf, rk);
            o.y = spike_step(u.y, buf, rk);
            o.z = spike_step(u.z, buf, rk);
            o.w = spike_step(u.w, buf, rk);
            S1[(size_t)(72 + k) * 131072 + nb0] = o;
        }
    }
}

// ---------------------------------------------------------------------------
// conv2 via MFMA (R15, verified): [4t][18][18][16ic] u8, tap-pair K-packing.
// ---------------------------------------------------------------------------
__global__ __launch_bounds__(256) void conv2_mfma_k(
    const unsigned int* __restrict__ s2u, const unsigned short* __restrict__ Wr2,
    float4* __restrict__ U, int b0, int nbl)
{
    __shared__ __align__(16) unsigned char pad[4 * 18 * 18 * 16];   // 20736
    const int tc = blockIdx.x;
    const int bl = blockIdx.z;
    const int b = b0 + bl;
    const int tid = threadIdx.x;
    const int wv = tid >> 6, lane = tid & 63;
    const int q = lane >> 4, n = lane & 15;
    const int PLANE_U = nbl * 8192;      // float4 per chunk

    unsigned int* lp = (unsigned int*)pad;
    for (int i = tid; i < 5184; i += 256) lp[i] = 0u;
    __syncthreads();
    const unsigned int* sb = s2u + (size_t)tc * 32768 + b * 4096;
    for (int e = tid; e < 4096; e += 256) {
        const unsigned int v = sb[e];
        const int c = e >> 8, pix = e & 255;
        const int base = (((pix >> 4) + 1) * 18 + ((pix & 15) + 1)) * 16 + c;
        pad[base]         = (unsigned char)(v & 0xFFu);
        pad[5184 + base]  = (unsigned char)((v >> 8) & 0xFFu);
        pad[10368 + base] = (unsigned char)((v >> 16) & 0xFFu);
        pad[15552 + base] = (unsigned char)(v >> 24);
    }
    __syncthreads();

    for (int i = 0; i < 4; ++i) {
        const int r = wv * 4 + i;        // pixel row (N-tile)
        f32x4 acc[2][4];                 // [oc-tile][t]
#pragma unroll
        for (int mt = 0; mt < 2; ++mt)
#pragma unroll
            for (int t = 0; t < 4; ++t) acc[mt][t] = (f32x4){0.f, 0.f, 0.f, 0.f};

        for (int kp = 0; kp < 5; ++kp) {
            short8 Af[6];   // [s][mt]
#pragma unroll
            for (int s = 0; s < 3; ++s)
#pragma unroll
                for (int mt = 0; mt < 2; ++mt)
                    Af[s * 2 + mt] = *(const short8*)(Wr2 + ((((s * 5 + kp) * 2 + mt) * 64 + lane) * 8));
            int tap = kp * 2 + (q >> 1);
            if (tap > 8) tap = 8;        // pad step: A is zero, address just valid
            const int dy = tap / 3, dx = tap % 3;
#pragma unroll
            for (int t = 0; t < 4; ++t) {
                const int off = ((t * 18 + r + dy) * 18 + (n + dx)) * 16 + (q & 1) * 8;
                const short8 Bf = bytes_to_bf16x8(*(const uint2*)(pad + off));
#pragma unroll
                for (int s = 0; s < 3; ++s)
#pragma unroll
                    for (int mt = 0; mt < 2; ++mt)
                        acc[mt][t] = __builtin_amdgcn_mfma_f32_16x16x32_bf16(
                            Af[s * 2 + mt], Bf, acc[mt][t], 0, 0, 0);
            }
        }

        const size_t ub = (size_t)tc * PLANE_U;
#pragma unroll
        for (int mt = 0; mt < 2; ++mt)
#pragma unroll
            for (int rr = 0; rr < 4; ++rr) {
                const int oc = mt * 16 + q * 4 + rr;
                const int nb = (bl * 32 + oc) * 256 + r * 16 + n;
                U[ub + nb] = make_float4(acc[mt][0][rr], acc[mt][1][rr], acc[mt][2][rr], acc[mt][3][rr]);
            }
    }
}

// ---------------------------------------------------------------------------
// conv3 via MFMA (R14, verified): [4t][10][10][32ic] u8 tile, k = tap*32+ic.
// ---------------------------------------------------------------------------
__global__ __launch_bounds__(256) void conv3_mfma_k(
    const unsigned int* __restrict__ s4u, const unsigned short* __restrict__ Wr,
    float4* __restrict__ U)
{
    __shared__ __align__(16) unsigned char pad[12800];   // [t][row10][col10][ic32]
    const int tc = blockIdx.x;
    const int bl = blockIdx.z;
    const int tid = threadIdx.x;
    const int wv = tid >> 6, lane = tid & 63;
    const int q = lane >> 4, n = lane & 15;

    unsigned int* lp = (unsigned int*)pad;
    for (int i = tid; i < 3200; i += 256) lp[i] = 0u;
    __syncthreads();
    const unsigned int* sb = s4u + (size_t)tc * 16384 + bl * 2048;
    for (int e = tid; e < 2048; e += 256) {
        const unsigned int v = sb[e];
        const int c = e >> 6, pix = e & 63;
        const int base = (((pix >> 3) + 1) * 10 + ((pix & 7) + 1)) * 32 + c;
        pad[base]        = (unsigned char)(v & 0xFFu);
        pad[3200 + base] = (unsigned char)((v >> 8) & 0xFFu);
        pad[6400 + base] = (unsigned char)((v >> 16) & 0xFFu);
        pad[9600 + base] = (unsigned char)(v >> 24);
    }
    __syncthreads();

    const int pixel = wv * 16 + n;
    const int py0 = pixel >> 3, px0 = pixel & 7;

    f32x4 acc[4][4];   // [oc-tile][t]
#pragma unroll
    for (int mt = 0; mt < 4; ++mt)
#pragma unroll
        for (int t = 0; t < 4; ++t) acc[mt][t] = (f32x4){0.f, 0.f, 0.f, 0.f};

    for (int ks = 0; ks < 9; ++ks) {
        const int dy = ks / 3, dx = ks % 3;
        short8 Af[12];
#pragma unroll
        for (int s = 0; s < 3; ++s)
#pragma unroll
            for (int mt = 0; mt < 4; ++mt)
                Af[s * 4 + mt] = *(const short8*)(Wr + ((((s * 9 + ks) * 4 + mt) * 64 + lane) * 8));
#pragma unroll
        for (int t = 0; t < 4; ++t) {
            const int off = ((t * 10 + py0 + dy) * 10 + (px0 + dx)) * 32 + q * 8;
            const short8 Bf = bytes_to_bf16x8(*(const uint2*)(pad + off));
#pragma unroll
            for (int s = 0; s < 3; ++s)
#pragma unroll
                for (int mt = 0; mt < 4; ++mt)
                    acc[mt][t] = __builtin_amdgcn_mfma_f32_16x16x32_bf16(
                        Af[s * 4 + mt], Bf, acc[mt][t], 0, 0, 0);
        }
    }

    const size_t ub = (size_t)tc * 32768 + (size_t)bl * 4096;
#pragma unroll
    for (int mt = 0; mt < 4; ++mt)
#pragma unroll
        for (int r = 0; r < 4; ++r) {
            const int oc = mt * 16 + q * 4 + r;
            const int nb = oc * 64 + wv * 16 + n;
            U[ub + nb] = make_float4(acc[mt][0][r], acc[mt][1][r], acc[mt][2][r], acc[mt][3][r]);
        }
}

// ---------------------------------------------------------------------------
// spike body: per-neuron scan. float4 per chunk in, uchar4 per chunk out.
// ---------------------------------------------------------------------------
__device__ __forceinline__ void spike_body(
    const float4* __restrict__ U, uchar4* __restrict__ S,
    int nneur, int sstride, int soff, const RefK& rk)
{
    const int n = blockIdx.x * 64 + threadIdx.x;
    const float4* up = U + n;
    uchar4* sp = S + soff + n;
    float buf[10];
#pragma unroll
    for (int r = 0; r < 10; ++r) buf[r] = 0.f;

    float4 ring[8];
#pragma unroll
    for (int r = 0; r < 8; ++r) ring[r] = up[(size_t)r * nneur];

#pragma unroll 8
    for (int ch = 0; ch < 72; ++ch) {
        const float4 cur = ring[ch & 7];
        const int pf = (ch + 8 < NCHUNK) ? ch + 8 : NCHUNK - 1;
        ring[ch & 7] = up[(size_t)pf * nneur];
        uchar4 o;
        o.x = spike_step(cur.x, buf, rk);
        o.y = spike_step(cur.y, buf, rk);
        o.z = spike_step(cur.z, buf, rk);
        o.w = spike_step(cur.w, buf, rk);
        sp[(size_t)ch * sstride] = o;
    }
#pragma unroll
    for (int ch = 72; ch < NCHUNK; ++ch) {
        const float4 cur = ring[ch & 7];
        uchar4 o;
        o.x = spike_step(cur.x, buf, rk);
        o.y = spike_step(cur.y, buf, rk);
        o.z = spike_step(cur.z, buf, rk);
        o.w = spike_step(cur.w, buf, rk);
        sp[(size_t)ch * sstride] = o;
    }
}

__global__ __launch_bounds__(64) void spike2_k(
    const float4* U, uchar4* S, int nneur, int sstride, int soff, RefK rk)
{ spike_body(U, S, nneur, sstride, soff, rk); }

__global__ __launch_bounds__(64) void spike3_k(
    const float4* U, uchar4* S, int nneur, int sstride, int soff, RefK rk)
{ spike_body(U, S, nneur, sstride, soff, rk); }

// ---------------------------------------------------------------------------
// pool(2)*11 + spike. Two 8-byte loads per chunk (x-pair rows). Ring-8.
// ---------------------------------------------------------------------------
__device__ __forceinline__ int bsum4(uint2 r0, uint2 r1, int k) {
    return (int)((r0.x >> (8 * k)) & 0xffu) + (int)((r0.y >> (8 * k)) & 0xffu)
         + (int)((r1.x >> (8 * k)) & 0xffu) + (int)((r1.y >> (8 * k)) & 0xffu);
}

template <int C, int H, int W>
__device__ __forceinline__ void pool_body(
    const uchar4* __restrict__ Sin, uchar4* __restrict__ Sout, const RefK& rk)
{
    constexpr int H2 = H / 2, W2 = W / 2;
    constexpr int SIN = 8 * C * H * W;     // chunk stride (uchar4 units)
    constexpr int SOUT = 8 * C * H2 * W2;
    const int n = blockIdx.x * 64 + threadIdx.x;   // exact multiple of 64
    const int x = n % W2;
    const int y = (n / W2) % H2;
    const int c = (n / (W2 * H2)) % C;
    const int b = n / (W2 * H2 * C);
    const int base = (((b * C + c) * H + 2 * y) * W + 2 * x);
    uchar4* q = Sout + n;

    float buf[10];
#pragma unroll
    for (int r = 0; r < 10; ++r) buf[r] = 0.f;

    uint2 r0[8], r1[8];
#pragma unroll
    for (int r = 0; r < 8; ++r) {
        r0[r] = *(const uint2*)(Sin + (size_t)r * SIN + base);
        r1[r] = *(const uint2*)(Sin + (size_t)r * SIN + base + W);
    }

#pragma unroll 8
    for (int ch = 0; ch < 72; ++ch) {
        const uint2 a0 = r0[ch & 7], a1 = r1[ch & 7];
        const int pf = (ch + 8 < NCHUNK) ? ch + 8 : NCHUNK - 1;
        r0[ch & 7] = *(const uint2*)(Sin + (size_t)pf * SIN + base);
        r1[ch & 7] = *(const uint2*)(Sin + (size_t)pf * SIN + base + W);
        uchar4 o;
        o.x = spike_step(11.0f * (float)bsum4(a0, a1, 0), buf, rk);
        o.y = spike_step(11.0f * (float)bsum4(a0, a1, 1), buf, rk);
        o.z = spike_step(11.0f * (float)bsum4(a0, a1, 2), buf, rk);
        o.w = spike_step(11.0f * (float)bsum4(a0, a1, 3), buf, rk);
        q[(size_t)ch * SOUT] = o;
    }
#pragma unroll
    for (int ch = 72; ch < NCHUNK; ++ch) {
        const uint2 a0 = r0[ch & 7], a1 = r1[ch & 7];
        uchar4 o;
        o.x = spike_step(11.0f * (float)bsum4(a0, a1, 0), buf, rk);
        o.y = spike_step(11.0f * (float)bsum4(a0, a1, 1), buf, rk);
        o.z = spike_step(11.0f * (float)bsum4(a0, a1, 2), buf, rk);
        o.w = spike_step(11.0f * (float)bsum4(a0, a1, 3), buf, rk);
        q[(size_t)ch * SOUT] = o;
    }
}

__global__ __launch_bounds__(64) void pool2_k(
    const uchar4* Sin, uchar4* Sout, RefK rk) { pool_body<16, 32, 32>(Sin, Sout, rk); }
__global__ __launch_bounds__(64) void pool4_k(
    const uchar4* Sin, uchar4* Sout, RefK rk) { pool_body<32, 16, 16>(Sin, Sout, rk); }

// ---------------------------------------------------------------------------
// dense u (R0-verified): one block per (tc, o, b).
// U6[tc][b*10+o][4] = sum_site wfc[o,site] * s5[tc][b*4096+site][4]
// ---------------------------------------------------------------------------
__global__ __launch_bounds__(64) void dense_k(
    const uchar4* __restrict__ S5, const float* __restrict__ WFC,
    float4* __restrict__ U6)
{
    const int tc = blockIdx.x, o = blockIdx.y, b = blockIdx.z;
    const int lane = threadIdx.x;
    float a0 = 0.f, a1 = 0.f, a2 = 0.f, a3 = 0.f;
    const uchar4* sb = S5 + (size_t)tc * 32768 + b * 4096;
    const float* wb = WFC + o * 4096;
    for (int i = 0; i < 64; ++i) {
        const int site = i * 64 + lane;
        const uchar4 s = sb[site];
        const float w = wb[site];
        a0 = fmaf(w, (float)s.x, a0);
        a1 = fmaf(w, (float)s.y, a1);
        a2 = fmaf(w, (float)s.z, a2);
        a3 = fmaf(w, (float)s.w, a3);
    }
#pragma unroll
    for (int m = 1; m < 64; m <<= 1) {
        a0 += __shfl_xor(a0, m, 64);
        a1 += __shfl_xor(a1, m, 64);
        a2 += __shfl_xor(a2, m, 64);
        a3 += __shfl_xor(a3, m, 64);
    }
    if (lane == 0)
        U6[(size_t)tc * 80 + b * 10 + o] = make_float4(a0, a1, a2, a3);
}

// final spike over 80 neurons; float4 chunks in, [n][t] fp32 out.
__global__ __launch_bounds__(128) void spike6_k(
    const float4* __restrict__ U6, float* __restrict__ Out, RefK rk)
{
    const int n = threadIdx.x;
    if (n >= 80) return;
    const float4* up = U6 + n;
    float* op = Out + (size_t)n * T_SAMPLE;
    float buf[10];
#pragma unroll
    for (int r = 0; r < 10; ++r) buf[r] = 0.f;

    float4 ring[8];
#pragma unroll
    for (int r = 0; r < 8; ++r) ring[r] = up[(size_t)r * 80];

#pragma unroll 8
    for (int ch = 0; ch < 72; ++ch) {
        const float4 cur = ring[ch & 7];
        const int pf = (ch + 8 < NCHUNK) ? ch + 8 : NCHUNK - 1;
        ring[ch & 7] = up[(size_t)pf * 80];
        float4 o;
        o.x = (float)spike_step(cur.x, buf, rk);
        o.y = (float)spike_step(cur.y, buf, rk);
        o.z = (float)spike_step(cur.z, buf, rk);
        o.w = (float)spike_step(cur.w, buf, rk);
        *(float4*)(op + ch * 4) = o;
    }
#pragma unroll
    for (int ch = 72; ch < NCHUNK; ++ch) {
        const float4 cur = ring[ch & 7];
        float4 o;
        o.x = (float)spike_step(cur.x, buf, rk);
        o.y = (float)spike_step(cur.y, buf, rk);
        o.z = (float)spike_step(cur.z, buf, rk);
        o.w = (float)spike_step(cur.w, buf, rk);
        *(float4*)(op + ch * 4) = o;
    }
}

extern "C" void kernel_launch(void* const* d_in, const int* in_sizes, int n_in,
                              void* d_out, int out_size, void* d_ws, size_t ws_size,
                              hipStream_t stream)
{
    const float* spikeIn = (const float*)d_in[0];  // [8,2,34,34,300]
    const float* w1 = (const float*)d_in[1];       // [16,2,5,5]
    const float* w2 = (const float*)d_in[2];       // [32,16,3,3]
    const float* w3 = (const float*)d_in[3];       // [64,32,3,3]
    const float* wfc = (const float*)d_in[4];      // [10,64,8,8]
    float* out = (float*)d_out;                    // [8,10,1,1,300]

    RefK rk;
    for (int t = 1; t <= 10; ++t)
        rk.v[t - 1] = (float)(-20.0 * (double)t * std::exp(1.0 - (double)t));

    // Workspace (layer 1 fused -> U only needed by conv2/conv3):
    //   U region: big tier 78.6 MB (conv2 nbl2=8) else 39.3 MB (nbl2=4).
    //   A region 39.3 MB: s1 / s3 / s5 (+ Wr/Wr2 at A+20 MB, prepped after
    //     pool2 when only s3 (<=19.7 MB) / s5 (<=9.8 MB) live there).
    //   B region 9.8 MB: X (5.55 MB) + Wr1 at B+5.57 MB; s2/s4 later.
    const size_t A_BYTES = 39321600;
    const size_t B_BYTES = 9830400;
    const size_t U6_BYTES = 96000;
    const size_t U_BIG = 78643200, U_SMALL = 39321600;
    const size_t TAIL = A_BYTES + B_BYTES + U6_BYTES;
    const bool big = ws_size >= U_BIG + TAIL;
    const size_t U_BYTES = big ? U_BIG : U_SMALL;

    char* ws = (char*)d_ws;
    float4* U = (float4*)ws;
    uchar4* A = (uchar4*)(ws + U_BYTES);
    uchar4* Bb = (uchar4*)(ws + U_BYTES + A_BYTES);
    float4* U6 = (float4*)(ws + U_BYTES + A_BYTES + B_BYTES);
    unsigned short* Wr = (unsigned short*)(ws + U_BYTES + 20971520);            // A+20MB
    unsigned short* Wr2 = (unsigned short*)(ws + U_BYTES + 20971520 + 131072);  // A+20MB+128K
    unsigned short* Wr1 = (unsigned short*)(ws + U_BYTES + A_BYTES + 5570560);  // B+5.57MB (past X)

    uchar4* X = Bb;   // 5.549 MB; dead after layer 1
    uchar4* s1 = A;
    uchar4* s2 = Bb;
    uchar4* s3 = A;   // s1 dead after pool2
    uchar4* s4 = Bb;  // s2 dead after conv2-u
    uchar4* s5 = A;   // s3 dead after pool4

    // ---- input transpose + conv1 weight prep ----
    transpose_in_k<<<18496 / 16, 256, 0, stream>>>(spikeIn, (unsigned int*)X);
    prep_w1_k<<<24, 256, 0, stream>>>(w1, Wr1);

    // ---- layer 1: producer-consumer fused conv+spike (window 4) ----
    {
        dim3 g1(64, 8);   // (pixel-group 2x8, batch) = 512 blocks x 512 thr
        conv1pc_k<<<g1, 512, 0, stream>>>((const unsigned int*)X, Wr1, s1, rk);
    }
    // ---- pool2 + spike ----
    pool2_k<<<32768 / 64, 64, 0, stream>>>(s1, s2, rk);
    // ---- conv2/conv3 weight preps (A+20MB region dead from here on) ----
    prep_w2_k<<<60, 256, 0, stream>>>(w2, Wr2);
    prep_w3_k<<<216, 256, 0, stream>>>(w3, Wr);
    // ---- layer 2: MFMA conv(16->32, k3) + spike (R0 verified path) ----
    const int nbl2 = big ? 8 : 4;
    for (int b0 = 0; b0 < 8; b0 += nbl2) {
        dim3 g2(NCHUNK, 1, nbl2);
        conv2_mfma_k<<<g2, 256, 0, stream>>>((const unsigned int*)s2, Wr2, U, b0, nbl2);
        const int nn = nbl2 * 8192;
        spike2_k<<<nn / 64, 64, 0, stream>>>(U, s3, nn, 65536, b0 * 8192, rk);
    }
    // ---- pool4 + spike ----
    pool4_k<<<16384 / 64, 64, 0, stream>>>(s3, s4, rk);
    // ---- layer 3: MFMA conv(32->64, k3) + spike, full batch ----
    {
        dim3 g3(NCHUNK, 1, 8);   // (tc, -, bl): 600 blocks
        conv3_mfma_k<<<g3, 256, 0, stream>>>((const unsigned int*)s4, Wr, U);
        spike3_k<<<32768 / 64, 64, 0, stream>>>(U, s5, 32768, 32768, 0, rk);
    }
    // ---- dense (R0 form: one block per (tc,o,b)) + final spike ----
    {
        dim3 g6(NCHUNK, 10, 8);
        dense_k<<<g6, 64, 0, stream>>>(s5, wfc, U6);
    }
    spike6_k<<<1, 128, 0, stream>>>(U6, out, rk);
}